// Round 1
// 633.255 us; speedup vs baseline: 1.0172x; 1.0172x over previous
//
#include <hip/hip_runtime.h>
#include <cstdint>

typedef __bf16 bf16x8 __attribute__((ext_vector_type(8)));
typedef float f32x4 __attribute__((ext_vector_type(4)));

__device__ __forceinline__ float b2f(unsigned short u) {
  union { uint32_t i; float f; } v; v.i = ((uint32_t)u) << 16; return v.f;
}
__device__ __forceinline__ unsigned short f2b(float f) {
  union { float f; uint32_t i; } v; v.f = f;
  uint32_t u = v.i;
  u += 0x7fffu + ((u >> 16) & 1u);   // round-to-nearest-even
  return (unsigned short)(u >> 16);
}

// async global->LDS, 16B per lane. LDS dest must be wave-uniform base + lane*16
// (our layouts are exactly lane-contiguous).
__device__ __forceinline__ void gload_lds16(const void* g, void* l) {
  __builtin_amdgcn_global_load_lds(
      (const __attribute__((address_space(1))) uint32_t*)(uintptr_t)g,
      (__attribute__((address_space(3))) uint32_t*)(uint32_t)(uintptr_t)l, 16, 0, 0);
}

// ---------------------------------------------------------------------------
// K0: W (fp32 1024x1024) -> Wb (bf16); block 0 also zeroes the BN-stat
// accumulators (gs[1024] | gs2[1024]) consumed by k_gemm's atomics.
// ---------------------------------------------------------------------------
__global__ __launch_bounds__(256) void k_wconv(const float* __restrict__ W,
                                               unsigned short* __restrict__ Wb,
                                               float* __restrict__ gstat) {
  if (blockIdx.x == 0) {
#pragma unroll
    for (int e = 0; e < 8; ++e) gstat[e * 256 + threadIdx.x] = 0.f;
  }
  const size_t idx = ((size_t)blockIdx.x * 256 + threadIdx.x) * 4;
  float4 d = *(const float4*)(W + idx);
  ushort4 o;
  o.x = f2b(d.x); o.y = f2b(d.y); o.z = f2b(d.z); o.w = f2b(d.w);
  *(ushort4*)(Wb + idx) = o;
}

// ---------------------------------------------------------------------------
// K1: Haar analysis fused with (a) transpose of scaling coeffs:
//   xs[p][b][c][8192] (fp32) -> sc_t[b][ls][j=p*128+c] (bf16), ls in [0,4096)
// and (b) the detail half of the OUTPUT (synthesis of l in [4096,8192) depends
// only on det pairs): out[row][4096+d], out[row][4097+d] from det[d],det[d+1].
// This removes k_synth_det's full 268 MB re-read of xs.
// sc tile: 64 j x 64 ls per block, LDS transpose (row stride 72 keeps 16B align)
// det path: direct float2 stores; successive a-iters fill contiguous 256B per
// row group, so L2 line-fill keeps DRAM write efficiency.
// ---------------------------------------------------------------------------
__global__ __launch_bounds__(256) void k_analysis(const float* __restrict__ xs,
                                                  const float* __restrict__ A,
                                                  const float* __restrict__ S,
                                                  unsigned short* __restrict__ sct,
                                                  float* __restrict__ out) {
  __shared__ __align__(16) unsigned short lt[64 * 72];
  const int t = threadIdx.x;
  const int bx = blockIdx.x;   // ls-tile 0..63
  const int by = blockIdx.y;   // j-tile 0..15
  const int bz = blockIdx.z;   // b
  const float a00 = A[0], a01 = A[1], a10 = A[2], a11 = A[3];
  const float s00 = S[0], s01 = S[1], s10 = S[2], s11 = S[3];
  const int r = t >> 2, s = t & 3;
  const int j = by * 64 + r;
  const int p = j >> 7, c = j & 127;
  const size_t row = (size_t)(p * 8 + bz) * 128 + c;
  const float* xr = xs + row * 8192 + bx * 128;
  float* orow = out + row * 8192 + 4096 + bx * 64;
#pragma unroll
  for (int a = 0; a < 8; ++a) {
    float4 d = *(const float4*)(xr + (s + 4 * a) * 4);
    int lsl = (s + 4 * a) * 2;
    lt[lsl * 72 + r]       = f2b(a00 * d.x + a01 * d.y);
    lt[(lsl + 1) * 72 + r] = f2b(a00 * d.z + a01 * d.w);
    float d0 = a10 * d.x + a11 * d.y;
    float d1 = a10 * d.z + a11 * d.w;
    float2 ov;
    ov.x = s00 * d0 + s01 * d1;
    ov.y = s10 * d0 + s11 * d1;
    *(float2*)(orow + lsl) = ov;   // lsl even -> 8B aligned
  }
  __syncthreads();
  const int lsr = t >> 2, ss = t & 3;
  uint4 o0 = *(const uint4*)&lt[lsr * 72 + ss * 16];
  uint4 o1 = *(const uint4*)&lt[lsr * 72 + ss * 16 + 8];
  size_t oidx = ((size_t)bz * 4096 + bx * 64 + lsr) * 1024 + by * 64 + ss * 16;
  *(uint4*)(sct + oidx) = o0;
  *(uint4*)(sct + oidx + 8) = o1;
}

// ---------------------------------------------------------------------------
// K2: smix[b][i][l] = sum_j Wb[i][j] * sc_t[b][l][j]   (bf16 MFMA, fp32 acc)
// m97 structure: BM=BN=128, BK=64, 256 thr (4 waves, 2x2), 16x16x32 bf16 MFMA,
// global_load_lds width 16, both operands k-contiguous in LDS.
// Epilogue additionally accumulates per-channel BN partial sums (sum, sumsq)
// over this block's 128-col tile into global fp32 accumulators -> removes
// k_stats' 64 MB re-read of smix.
// ---------------------------------------------------------------------------
__global__ __launch_bounds__(256) void k_gemm(const unsigned short* __restrict__ Wb,
                                              const unsigned short* __restrict__ sct,
                                              unsigned short* __restrict__ smix,
                                              float* __restrict__ gsum,
                                              float* __restrict__ gsum2) {
  __shared__ __align__(16) unsigned short lA[128 * 64];  // [i_loc][k_loc]
  __shared__ __align__(16) unsigned short lB[128 * 64];  // [l_loc][k_loc]
  __shared__ float wsum[4][64], wsum2[4][64];
  const int t = threadIdx.x;
  const int i0 = blockIdx.x * 128;   // i-block fastest -> per-XCD W-slice locality
  const int l0 = blockIdx.y * 128;
  const int bz = blockIdx.z;
  const int lane = t & 63, wv = t >> 6;
  const int wm = wv & 1, wn = wv >> 1;
  const int lm = lane & 15, q = lane >> 4;
  const int srow = t >> 3;           // 0..31
  const int scol = (t & 7) * 8;      // element col (16B)
  f32x4 acc[4][4] = {};
  for (int kt = 0; kt < 16; ++kt) {
    __syncthreads();
    const int k0 = kt * 64;
#pragma unroll
    for (int a = 0; a < 4; ++a) {
      int rowa = a * 32 + srow;
      gload_lds16(Wb + ((size_t)(i0 + rowa) * 1024 + k0 + scol),
                  (char*)lA + a * 4096 + t * 16);
      gload_lds16(sct + (((size_t)bz * 4096 + l0 + rowa) * 1024 + k0 + scol),
                  (char*)lB + a * 4096 + t * 16);
    }
    __syncthreads();
#pragma unroll
    for (int kk = 0; kk < 2; ++kk) {
      bf16x8 aF[4], bF[4];
#pragma unroll
      for (int mi = 0; mi < 4; ++mi)
        aF[mi] = *(const bf16x8*)&lA[(wm * 64 + mi * 16 + lm) * 64 + kk * 32 + q * 8];
#pragma unroll
      for (int ni = 0; ni < 4; ++ni)
        bF[ni] = *(const bf16x8*)&lB[(wn * 64 + ni * 16 + lm) * 64 + kk * 32 + q * 8];
#pragma unroll
      for (int mi = 0; mi < 4; ++mi)
#pragma unroll
        for (int ni = 0; ni < 4; ++ni)
          acc[mi][ni] = __builtin_amdgcn_mfma_f32_16x16x32_bf16(aF[mi], bF[ni], acc[mi][ni], 0, 0, 0);
    }
  }
  // C/D layout (m89-verified): col = lane&15, row = (lane>>4)*4 + reg
  const size_t base = ((size_t)bz * 1024 + i0 + wm * 64) * 4096 + (size_t)(l0 + wn * 64);
#pragma unroll
  for (int mi = 0; mi < 4; ++mi)
#pragma unroll
    for (int ni = 0; ni < 4; ++ni)
#pragma unroll
      for (int rr = 0; rr < 4; ++rr)
        smix[base + (size_t)(mi * 16 + q * 4 + rr) * 4096 + ni * 16 + lm] = f2b(acc[mi][ni][rr]);
  // --- BN partial stats over this block's 128x128 tile ---
  // row_local = wm*64 + mi*16 + q*4 + rr ; cols = wn*64 + ni*16 + lm
#pragma unroll
  for (int mi = 0; mi < 4; ++mi)
#pragma unroll
    for (int rr = 0; rr < 4; ++rr) {
      float sv = 0.f, sq = 0.f;
#pragma unroll
      for (int ni = 0; ni < 4; ++ni) {
        float v = acc[mi][ni][rr];
        sv += v; sq += v * v;
      }
#pragma unroll
      for (int o = 1; o < 16; o <<= 1) {   // reduce over lm (lanes q*16+0..15)
        sv += __shfl_xor(sv, o, 64);
        sq += __shfl_xor(sq, o, 64);
      }
      if (lm == 0) {
        wsum[wv][mi * 16 + q * 4 + rr] = sv;
        wsum2[wv][mi * 16 + q * 4 + rr] = sq;
      }
    }
  __syncthreads();
  if (t < 128) {
    const int rl = t & 63;
    const int wmi = t >> 6;              // 0: waves {0,2} (wm=0); 1: waves {1,3}
    float sv = wsum[wmi][rl] + wsum[wmi + 2][rl];
    float sq = wsum2[wmi][rl] + wsum2[wmi + 2][rl];
    unsafeAtomicAdd(&gsum[i0 + t], sv);
    unsafeAtomicAdd(&gsum2[i0 + t], sq);
  }
}

// ---------------------------------------------------------------------------
// K3: finalize BN stats -> folded scale/shift (tiny: 1024 channels).
// ---------------------------------------------------------------------------
__global__ __launch_bounds__(256) void k_bnfin(const float* __restrict__ gsum,
                                               const float* __restrict__ gsum2,
                                               const float* __restrict__ gamma,
                                               const float* __restrict__ beta,
                                               float* __restrict__ scale,
                                               float* __restrict__ shift) {
  const int i = blockIdx.x * 256 + threadIdx.x;
  const float inv = 1.0f / 32768.0f;
  float mean = gsum[i] * inv;
  float var = gsum2[i] * inv - mean * mean;   // biased, matches jnp .var
  float rstd = rsqrtf(var + 1e-5f);
  float g = gamma[i] * rstd;
  scale[i] = g;
  shift[i] = beta[i] - mean * g;
}

// ---------------------------------------------------------------------------
// K4: first output half (l in [0,4096)): BN+GELU(exact erf) on smix pairs,
// then synthesis butterfly with S. Fully coalesced both sides. fp32 out.
// ---------------------------------------------------------------------------
__global__ __launch_bounds__(256) void k_synth_sc(const unsigned short* __restrict__ smix,
                                                  const float* __restrict__ S,
                                                  const float* __restrict__ scale,
                                                  const float* __restrict__ shift,
                                                  float* __restrict__ out) {
  const float s00 = S[0], s01 = S[1], s10 = S[2], s11 = S[3];
  const size_t tid = (size_t)blockIdx.x * 256 + threadIdx.x;
  const size_t f = tid * 16;                 // flat index into smix [b][i][l]
  const int b = (int)(f >> 22);
  const int i = (int)((f >> 12) & 1023);
  const int l0 = (int)(f & 4095);
  const float sc_i = scale[i], sh_i = shift[i];
  union { uint4 v; unsigned short u[8]; } d0, d1;
  d0.v = *(const uint4*)(smix + f);
  d1.v = *(const uint4*)(smix + f + 8);
  float cv[16];
#pragma unroll
  for (int e = 0; e < 8; ++e) {
    float z0 = b2f(d0.u[e]) * sc_i + sh_i;
    cv[e] = 0.5f * z0 * (1.0f + erff(z0 * 0.7071067811865475f));
    float z1 = b2f(d1.u[e]) * sc_i + sh_i;
    cv[8 + e] = 0.5f * z1 * (1.0f + erff(z1 * 0.7071067811865475f));
  }
  float ov[16];
#pragma unroll
  for (int m = 0; m < 8; ++m) {
    float c0 = cv[2 * m], c1 = cv[2 * m + 1];
    ov[2 * m] = s00 * c0 + s01 * c1;
    ov[2 * m + 1] = s10 * c0 + s11 * c1;
  }
  const int p = i >> 7, cc = i & 127;
  size_t ob = ((size_t)(p * 8 + b) * 128 + cc) * 8192 + l0;
#pragma unroll
  for (int v = 0; v < 4; ++v)
    *(float4*)(out + ob + v * 4) = *(float4*)&ov[v * 4];
}

extern "C" void kernel_launch(void* const* d_in, const int* in_sizes, int n_in,
                              void* d_out, int out_size, void* d_ws, size_t ws_size,
                              hipStream_t stream) {
  const float* xs    = (const float*)d_in[0];
  const float* A     = (const float*)d_in[1];
  const float* S     = (const float*)d_in[2];
  const float* W     = (const float*)d_in[3];
  const float* gamma = (const float*)d_in[4];
  const float* beta  = (const float*)d_in[5];
  float* out = (float*)d_out;
  char* ws = (char*)d_ws;
  unsigned short* sct  = (unsigned short*)ws;                                // 64 MB sc_t[b][l][j] bf16
  unsigned short* smix = (unsigned short*)(ws + (size_t)64 * 1024 * 1024);   // 64 MB smix[b][i][l] bf16
  unsigned short* Wb   = (unsigned short*)(ws + (size_t)128 * 1024 * 1024);  // 2 MB W bf16
  float* gsum  = (float*)(ws + (size_t)130 * 1024 * 1024);                   // 4 KB BN sum
  float* gsum2 = gsum + 1024;                                                // 4 KB BN sumsq
  float* scale = gsum + 2048;                                                // 4 KB
  float* shift = gsum + 3072;                                                // 4 KB

  hipLaunchKernelGGL(k_wconv, dim3(1024), dim3(256), 0, stream, W, Wb, gsum);
  hipLaunchKernelGGL(k_analysis, dim3(64, 16, 8), dim3(256), 0, stream, xs, A, S, sct, out);
  hipLaunchKernelGGL(k_gemm, dim3(8, 32, 8), dim3(256), 0, stream, Wb, sct, smix, gsum, gsum2);
  hipLaunchKernelGGL(k_bnfin, dim3(4), dim3(256), 0, stream, gsum, gsum2, gamma, beta, scale, shift);
  hipLaunchKernelGGL(k_synth_sc, dim3(8192), dim3(256), 0, stream, smix, S, scale, shift, out);
}

// Round 2
// 616.329 us; speedup vs baseline: 1.0451x; 1.0275x over previous
//
#include <hip/hip_runtime.h>
#include <cstdint>

typedef __bf16 bf16x8 __attribute__((ext_vector_type(8)));
typedef float f32x4 __attribute__((ext_vector_type(4)));

__device__ __forceinline__ float b2f(unsigned short u) {
  union { uint32_t i; float f; } v; v.i = ((uint32_t)u) << 16; return v.f;
}
__device__ __forceinline__ unsigned short f2b(float f) {
  union { float f; uint32_t i; } v; v.f = f;
  uint32_t u = v.i;
  u += 0x7fffu + ((u >> 16) & 1u);   // round-to-nearest-even
  return (unsigned short)(u >> 16);
}

// async global->LDS, 16B per lane. LDS dest must be wave-uniform base + lane*16.
__device__ __forceinline__ void gload_lds16(const void* g, void* l) {
  __builtin_amdgcn_global_load_lds(
      (const __attribute__((address_space(1))) uint32_t*)(uintptr_t)g,
      (__attribute__((address_space(3))) uint32_t*)(uint32_t)(uintptr_t)l, 16, 0, 0);
}

#define GBAR() do { __builtin_amdgcn_sched_barrier(0); __builtin_amdgcn_s_barrier(); __builtin_amdgcn_sched_barrier(0); } while (0)

// ---------------------------------------------------------------------------
// K0: W (fp32 1024x1024) -> Wb (bf16); block 0 also zeroes BN-stat accums.
// ---------------------------------------------------------------------------
__global__ __launch_bounds__(256) void k_wconv(const float* __restrict__ W,
                                               unsigned short* __restrict__ Wb,
                                               float* __restrict__ gstat) {
  if (blockIdx.x == 0) {
#pragma unroll
    for (int e = 0; e < 8; ++e) gstat[e * 256 + threadIdx.x] = 0.f;
  }
  const size_t idx = ((size_t)blockIdx.x * 256 + threadIdx.x) * 4;
  float4 d = *(const float4*)(W + idx);
  ushort4 o;
  o.x = f2b(d.x); o.y = f2b(d.y); o.z = f2b(d.z); o.w = f2b(d.w);
  *(ushort4*)(Wb + idx) = o;
}

// ---------------------------------------------------------------------------
// K1: Haar analysis fused with (a) transposed scaling coeffs -> sct (bf16)
// and (b) the detail half of the output (synthesis of l in [4096,8192)).
// ---------------------------------------------------------------------------
__global__ __launch_bounds__(256) void k_analysis(const float* __restrict__ xs,
                                                  const float* __restrict__ A,
                                                  const float* __restrict__ S,
                                                  unsigned short* __restrict__ sct,
                                                  float* __restrict__ out) {
  __shared__ __align__(16) unsigned short lt[64 * 72];
  const int t = threadIdx.x;
  const int bx = blockIdx.x;   // ls-tile 0..63
  const int by = blockIdx.y;   // j-tile 0..15
  const int bz = blockIdx.z;   // b
  const float a00 = A[0], a01 = A[1], a10 = A[2], a11 = A[3];
  const float s00 = S[0], s01 = S[1], s10 = S[2], s11 = S[3];
  const int r = t >> 2, s = t & 3;
  const int j = by * 64 + r;
  const int p = j >> 7, c = j & 127;
  const size_t row = (size_t)(p * 8 + bz) * 128 + c;
  const float* xr = xs + row * 8192 + bx * 128;
  float* orow = out + row * 8192 + 4096 + bx * 64;
#pragma unroll
  for (int a = 0; a < 8; ++a) {
    float4 d = *(const float4*)(xr + (s + 4 * a) * 4);
    int lsl = (s + 4 * a) * 2;
    lt[lsl * 72 + r]       = f2b(a00 * d.x + a01 * d.y);
    lt[(lsl + 1) * 72 + r] = f2b(a00 * d.z + a01 * d.w);
    float d0 = a10 * d.x + a11 * d.y;
    float d1 = a10 * d.z + a11 * d.w;
    float2 ov;
    ov.x = s00 * d0 + s01 * d1;
    ov.y = s10 * d0 + s11 * d1;
    *(float2*)(orow + lsl) = ov;
  }
  __syncthreads();
  const int lsr = t >> 2, ss = t & 3;
  uint4 o0 = *(const uint4*)&lt[lsr * 72 + ss * 16];
  uint4 o1 = *(const uint4*)&lt[lsr * 72 + ss * 16 + 8];
  size_t oidx = ((size_t)bz * 4096 + bx * 64 + lsr) * 1024 + by * 64 + ss * 16;
  *(uint4*)(sct + oidx) = o0;
  *(uint4*)(sct + oidx + 8) = o1;
}

// ---------------------------------------------------------------------------
// K2: smix[b][i][l] = sum_j Wb[i][j] * sc_t[b][l][j]   (bf16 MFMA, fp32 acc)
// 256x256 tile, BK=64, 8 waves (2Mx4N), 512 thr, 8-phase schedule
// (T2 swizzle + T3/T4 counted vmcnt + T5 setprio). LDS: 2 dbuf x (A 32K + B
// 32K) = 128 KiB + 8 KiB stats. Swizzle: byte ^= ((row>>1)&7)<<4 — involution,
// 16B-block-preserving; applied on the GLOBAL source (gload_lds dest linear)
// and on ds_read addresses -> conflict-free b128 reads (each 16-lane group
// spreads over all 32 banks).
// Epilogue: per-channel BN partial sums -> global atomics.
// ---------------------------------------------------------------------------
__device__ __forceinline__ void stage_half(const unsigned short* __restrict__ g,
                                           size_t row0, int kt, char* tile, int h, int t) {
#pragma unroll
  for (int a = 0; a < 2; ++a) {
    int r = a * 64 + (t >> 3);          // row within half 0..127
    int c2 = (t & 7) * 16;              // byte col within 128B row
    int c2s = c2 ^ (((r >> 1) & 7) << 4);
    gload_lds16((const char*)g + (row0 + (size_t)(h * 128 + r)) * 2048 + kt * 128 + c2s,
                tile + h * 16384 + (a * 512 + t) * 16);
  }
}

__device__ __forceinline__ bf16x8 frag(const char* tile, int row, int kk, int q) {
  int o = row * 128 + kk * 64 + q * 16;
  o ^= ((row >> 1) & 7) << 4;
  return *(const bf16x8*)(tile + o);
}

__device__ __forceinline__ void load_a(bf16x8 (&af)[4][2], const char* tile, int rbase,
                                       int lm, int q) {
#pragma unroll
  for (int m2 = 0; m2 < 4; ++m2)
#pragma unroll
    for (int kk = 0; kk < 2; ++kk)
      af[m2][kk] = frag(tile, rbase + m2 * 16 + lm, kk, q);
}
__device__ __forceinline__ void load_b(bf16x8 (&bf)[2][2], const char* tile, int rbase,
                                       int lm, int q) {
#pragma unroll
  for (int n2 = 0; n2 < 2; ++n2)
#pragma unroll
    for (int kk = 0; kk < 2; ++kk)
      bf[n2][kk] = frag(tile, rbase + n2 * 16 + lm, kk, q);
}
__device__ __forceinline__ void mfma_quad(f32x4 (&acc)[8][4], const bf16x8 (&af)[4][2],
                                          const bf16x8 (&bf)[2][2], int mh, int nh) {
  __builtin_amdgcn_s_setprio(1);
#pragma unroll
  for (int m2 = 0; m2 < 4; ++m2)
#pragma unroll
    for (int n2 = 0; n2 < 2; ++n2)
#pragma unroll
      for (int kk = 0; kk < 2; ++kk)
        acc[mh * 4 + m2][nh * 2 + n2] = __builtin_amdgcn_mfma_f32_16x16x32_bf16(
            af[m2][kk], bf[n2][kk], acc[mh * 4 + m2][nh * 2 + n2], 0, 0, 0);
  __builtin_amdgcn_s_setprio(0);
}

__global__ __launch_bounds__(512, 2) void k_gemm(const unsigned short* __restrict__ Wb,
                                                 const unsigned short* __restrict__ sct,
                                                 unsigned short* __restrict__ smix,
                                                 float* __restrict__ gsum,
                                                 float* __restrict__ gsum2) {
  extern __shared__ char lds[];
  char* bA0 = lds;
  char* bB0 = lds + 32768;
  char* bA1 = lds + 65536;
  char* bB1 = lds + 98304;
  float* wsum  = (float*)(lds + 131072);   // [8][128]
  float* wsum2 = wsum + 1024;
  const int t = threadIdx.x;
  const int i0 = blockIdx.x * 256;
  const int l0 = blockIdx.y * 256;
  const int bz = blockIdx.z;
  const int lane = t & 63, wv = t >> 6;
  const int wm = wv >> 2, wn = wv & 3;     // 2 x 4 wave grid
  const int lm = lane & 15, q = lane >> 4;
  const size_t arow0 = (size_t)i0;
  const size_t brow0 = (size_t)bz * 4096 + l0;
  f32x4 acc[8][4] = {};

  // prologue: tile0 fully + A0 of tile1 (5 half-tiles, 10 loads/thread)
  stage_half(Wb,  arow0, 0, bA0, 0, t);
  stage_half(sct, brow0, 0, bB0, 0, t);
  stage_half(Wb,  arow0, 0, bA0, 1, t);
  stage_half(sct, brow0, 0, bB0, 1, t);
  stage_half(Wb,  arow0, 1, bA1, 0, t);
  asm volatile("s_waitcnt vmcnt(2)" ::: "memory");
  __builtin_amdgcn_s_barrier();
  __builtin_amdgcn_sched_barrier(0);

#pragma unroll 1
  for (int it = 0; it < 8; ++it) {
    const int u = (2 * it + 1) & 15;   // tile staged ph1-3 -> dbuf1
    const int v = (2 * it + 2) & 15;   // tile staged ph4-7 -> dbuf0
    const int w = (2 * it + 3) & 15;   // A0 staged ph8     -> dbuf1
    bf16x8 a03[4][2], a47[4][2], b01[2][2], b23[2][2];
    // ph1: quadrant (0,0) of even tile; stage B0(u)
    load_a(a03, bA0, wm * 128 + 0, lm, q);
    load_b(b01, bB0, wn * 64 + 0, lm, q);
    stage_half(sct, brow0, u, bB1, 0, t);
    GBAR(); mfma_quad(acc, a03, b01, 0, 0); GBAR();
    // ph2: (0,1); stage A1(u)
    load_b(b23, bB0, wn * 64 + 32, lm, q);
    stage_half(Wb, arow0, u, bA1, 1, t);
    GBAR(); mfma_quad(acc, a03, b23, 0, 1); GBAR();
    // ph3: (1,1); stage B1(u)
    load_a(a47, bA0, wm * 128 + 64, lm, q);
    stage_half(sct, brow0, u, bB1, 1, t);
    GBAR(); mfma_quad(acc, a47, b23, 1, 1); GBAR();
    // ph4: (1,0) (operands all in regs); stage A0(v); drain to 2
    stage_half(Wb, arow0, v, bA0, 0, t);
    asm volatile("s_waitcnt vmcnt(2)" ::: "memory");
    GBAR(); mfma_quad(acc, a47, b01, 1, 0); GBAR();
    // ph5: (0,0) of odd tile; stage B0(v)
    load_a(a03, bA1, wm * 128 + 0, lm, q);
    load_b(b01, bB1, wn * 64 + 0, lm, q);
    stage_half(sct, brow0, v, bB0, 0, t);
    GBAR(); mfma_quad(acc, a03, b01, 0, 0); GBAR();
    // ph6: (0,1); stage A1(v)
    load_b(b23, bB1, wn * 64 + 32, lm, q);
    stage_half(Wb, arow0, v, bA0, 1, t);
    GBAR(); mfma_quad(acc, a03, b23, 0, 1); GBAR();
    // ph7: (1,1); stage B1(v)
    load_a(a47, bA1, wm * 128 + 64, lm, q);
    stage_half(sct, brow0, v, bB0, 1, t);
    GBAR(); mfma_quad(acc, a47, b23, 1, 1); GBAR();
    // ph8: (1,0); stage A0(w); drain to 2
    stage_half(Wb, arow0, w, bA1, 0, t);
    asm volatile("s_waitcnt vmcnt(2)" ::: "memory");
    GBAR(); mfma_quad(acc, a47, b01, 1, 0); GBAR();
  }
  asm volatile("s_waitcnt vmcnt(0)" ::: "memory");
  __builtin_amdgcn_s_barrier();

  // C store: row = i0 + wm*128 + mi*16 + q*4 + rr ; col = l0 + wn*64 + ni*16 + lm
  const size_t base = ((size_t)bz * 1024 + i0 + wm * 128) * 4096 + (size_t)(l0 + wn * 64);
#pragma unroll
  for (int mi = 0; mi < 8; ++mi)
#pragma unroll
    for (int ni = 0; ni < 4; ++ni)
#pragma unroll
      for (int rr = 0; rr < 4; ++rr)
        smix[base + (size_t)(mi * 16 + q * 4 + rr) * 4096 + ni * 16 + lm] = f2b(acc[mi][ni][rr]);

  // BN partial stats over this block's 256x256 tile
#pragma unroll
  for (int mi = 0; mi < 8; ++mi)
#pragma unroll
    for (int rr = 0; rr < 4; ++rr) {
      float sv = 0.f, sq = 0.f;
#pragma unroll
      for (int ni = 0; ni < 4; ++ni) {
        float vv = acc[mi][ni][rr];
        sv += vv; sq += vv * vv;
      }
#pragma unroll
      for (int o = 1; o < 16; o <<= 1) {
        sv += __shfl_xor(sv, o, 64);
        sq += __shfl_xor(sq, o, 64);
      }
      if (lm == 0) {
        wsum[wv * 128 + mi * 16 + q * 4 + rr] = sv;
        wsum2[wv * 128 + mi * 16 + q * 4 + rr] = sq;
      }
    }
  __syncthreads();
  if (t < 256) {
    const int wmr = t >> 7, rl = t & 127;
    float sv = 0.f, sq = 0.f;
#pragma unroll
    for (int wnn = 0; wnn < 4; ++wnn) {
      sv += wsum[(wmr * 4 + wnn) * 128 + rl];
      sq += wsum2[(wmr * 4 + wnn) * 128 + rl];
    }
    unsafeAtomicAdd(&gsum[i0 + t], sv);
    unsafeAtomicAdd(&gsum2[i0 + t], sq);
  }
}

// ---------------------------------------------------------------------------
// K3: finalize BN stats -> folded scale/shift.
// ---------------------------------------------------------------------------
__global__ __launch_bounds__(256) void k_bnfin(const float* __restrict__ gsum,
                                               const float* __restrict__ gsum2,
                                               const float* __restrict__ gamma,
                                               const float* __restrict__ beta,
                                               float* __restrict__ scale,
                                               float* __restrict__ shift) {
  const int i = blockIdx.x * 256 + threadIdx.x;
  const float inv = 1.0f / 32768.0f;
  float mean = gsum[i] * inv;
  float var = gsum2[i] * inv - mean * mean;
  float rstd = rsqrtf(var + 1e-5f);
  float g = gamma[i] * rstd;
  scale[i] = g;
  shift[i] = beta[i] - mean * g;
}

// ---------------------------------------------------------------------------
// K4: first output half: BN+GELU(exact erf) on smix pairs + synthesis.
// ---------------------------------------------------------------------------
__global__ __launch_bounds__(256) void k_synth_sc(const unsigned short* __restrict__ smix,
                                                  const float* __restrict__ S,
                                                  const float* __restrict__ scale,
                                                  const float* __restrict__ shift,
                                                  float* __restrict__ out) {
  const float s00 = S[0], s01 = S[1], s10 = S[2], s11 = S[3];
  const size_t tid = (size_t)blockIdx.x * 256 + threadIdx.x;
  const size_t f = tid * 16;
  const int b = (int)(f >> 22);
  const int i = (int)((f >> 12) & 1023);
  const int l0 = (int)(f & 4095);
  const float sc_i = scale[i], sh_i = shift[i];
  union { uint4 v; unsigned short u[8]; } d0, d1;
  d0.v = *(const uint4*)(smix + f);
  d1.v = *(const uint4*)(smix + f + 8);
  float cv[16];
#pragma unroll
  for (int e = 0; e < 8; ++e) {
    float z0 = b2f(d0.u[e]) * sc_i + sh_i;
    cv[e] = 0.5f * z0 * (1.0f + erff(z0 * 0.7071067811865475f));
    float z1 = b2f(d1.u[e]) * sc_i + sh_i;
    cv[8 + e] = 0.5f * z1 * (1.0f + erff(z1 * 0.7071067811865475f));
  }
  float ov[16];
#pragma unroll
  for (int m = 0; m < 8; ++m) {
    float c0 = cv[2 * m], c1 = cv[2 * m + 1];
    ov[2 * m] = s00 * c0 + s01 * c1;
    ov[2 * m + 1] = s10 * c0 + s11 * c1;
  }
  const int p = i >> 7, cc = i & 127;
  size_t ob = ((size_t)(p * 8 + b) * 128 + cc) * 8192 + l0;
#pragma unroll
  for (int v = 0; v < 4; ++v)
    *(float4*)(out + ob + v * 4) = *(float4*)&ov[v * 4];
}

extern "C" void kernel_launch(void* const* d_in, const int* in_sizes, int n_in,
                              void* d_out, int out_size, void* d_ws, size_t ws_size,
                              hipStream_t stream) {
  const float* xs    = (const float*)d_in[0];
  const float* A     = (const float*)d_in[1];
  const float* S     = (const float*)d_in[2];
  const float* W     = (const float*)d_in[3];
  const float* gamma = (const float*)d_in[4];
  const float* beta  = (const float*)d_in[5];
  float* out = (float*)d_out;
  char* ws = (char*)d_ws;
  unsigned short* sct  = (unsigned short*)ws;                                // 64 MB
  unsigned short* smix = (unsigned short*)(ws + (size_t)64 * 1024 * 1024);   // 64 MB
  unsigned short* Wb   = (unsigned short*)(ws + (size_t)128 * 1024 * 1024);  // 2 MB
  float* gsum  = (float*)(ws + (size_t)130 * 1024 * 1024);                   // 4 KB
  float* gsum2 = gsum + 1024;                                                // 4 KB
  float* scale = gsum + 2048;
  float* shift = gsum + 3072;

  hipLaunchKernelGGL(k_wconv, dim3(1024), dim3(256), 0, stream, W, Wb, gsum);
  hipLaunchKernelGGL(k_analysis, dim3(64, 16, 8), dim3(256), 0, stream, xs, A, S, sct, out);
  hipLaunchKernelGGL(k_gemm, dim3(4, 16, 8), dim3(512), 139264, stream, Wb, sct, smix, gsum, gsum2);
  hipLaunchKernelGGL(k_bnfin, dim3(4), dim3(256), 0, stream, gsum, gsum2, gamma, beta, scale, shift);
  hipLaunchKernelGGL(k_synth_sc, dim3(8192), dim3(256), 0, stream, smix, S, scale, shift, out);
}